// Round 8
// baseline (414.446 us; speedup 1.0000x reference)
//
#include <hip/hip_runtime.h>

namespace {

constexpr int C    = 64;    // input channels
constexpr int H    = 448;   // rows (= conv groups)
constexpr int Wd   = 608;   // width
constexpr int K    = 32;    // stage-1 classes
constexpr int B    = 2;     // batch
constexpr int COLS = 128;   // w-columns per block (4 waves x 32 cols)
constexpr int NTILE = 5;            // ceil(608/128)
constexpr int NBLK  = H * NTILE;    // 2240, % 8 == 0 -> bijective XCD swizzle

constexpr size_t W2T_BYTES = (size_t)H * C * C * sizeof(float);  // 7.3 MB

__device__ __forceinline__ float lrelu(float v) {
    return v >= 0.0f ? v : 0.01f * v;
}

// One-shot 64x64 transpose per h: W2T[h][c][o] = W2[h][o][c].
__global__ __launch_bounds__(256)
void transpose_w2(const float* __restrict__ W2, float* __restrict__ W2T) {
    __shared__ float t[C][C + 1];
    const int h = blockIdx.x;
    const float* __restrict__ in  = W2  + (size_t)h * C * C;
    float* __restrict__       op  = W2T + (size_t)h * C * C;
    const int tid = threadIdx.x;
#pragma unroll
    for (int k = 0; k < (C * C) / 256; ++k) {
        const int idx = tid + k * 256;
        t[idx >> 6][idx & 63] = in[idx];
    }
    __syncthreads();
#pragma unroll
    for (int k = 0; k < (C * C) / 256; ++k) {
        const int idx = tid + k * 256;
        op[idx] = t[idx & 63][idx >> 6];
    }
}

// Lane = (col-slot, channel-quarter). Each lane owns 16 channels of
// 4 pixels (2 batches x 2 cols) -> every LDS weight float4 feeds 4
// pixels (vs 2 in prior round): per-wave LDS return traffic ~halved.
// Quarter-sums combined with shfl_xor(16)+shfl_xor(32). W3 is read
// from global (L2-hot after XCD swizzle) -> LDS = 32 KB.
// x is scoped to layers 1+2 and reloaded (L2/L3-hot) for the reg
// step to keep peak regs ~<=150 (3 waves/SIMD, no spill).
template <bool USE_WT>
__global__ __launch_bounds__(256, 3)
void reg1stage_kernel(const float* __restrict__ x,
                      const float* __restrict__ W1, const float* __restrict__ b1,
                      const float* __restrict__ W2orT, const float* __restrict__ b2,
                      const float* __restrict__ W3, const float* __restrict__ b3,
                      const float* __restrict__ Wr, const float* __restrict__ br,
                      float* __restrict__ out)
{
    __shared__ float sW1[C * C];   // 16 KB
    __shared__ float sW2[C * C];   // 16 KB (transposed if USE_WT) -> 32 KB total

    const int tid = threadIdx.x;

    // XCD swizzle: 280 consecutive blocks (56 h, ~3.2 MB weights) per XCD.
    const int wg   = blockIdx.x;
    const int swz  = (wg & 7) * (NBLK / 8) + (wg >> 3);
    const int h    = swz / NTILE;
    const int tile = swz - NTILE * h;

    const int wave = tid >> 6;          // 4 waves/block
    const int lane = tid & 63;
    const int cpos = lane & 15;         // col slot within wave
    const int qtr  = lane >> 4;         // channel quarter
    const int cb   = qtr * 16;          // this lane's channel base
    const int w0   = tile * COLS + wave * 32 + cpos;
    const int w1   = w0 + 16;
    const bool v0  = (w0 < Wd);
    const bool v1  = (w1 < Wd);
    const int wc0  = v0 ? w0 : (Wd - 1);    // clamp; no early return (barrier)
    const int wc1  = v1 ? w1 : (Wd - 1);

    const size_t HW = (size_t)H * Wd;
    const float* __restrict__ W1h = W1    + (size_t)h * C * C;
    const float* __restrict__ W2h = W2orT + (size_t)h * C * C;
    const float* __restrict__ W3h = W3    + (size_t)h * K * C;
    const float* __restrict__ b1h = b1 + (size_t)h * C;
    const float* __restrict__ b2h = b2 + (size_t)h * C;
    const float* __restrict__ b3h = b3 + (size_t)h * K;

    // x column bases for this lane's channel quarter
    const float* __restrict__ xb0 = x + (((size_t)0 * C + cb) * H + h) * Wd;
    const float* __restrict__ xb1 = x + (((size_t)1 * C + cb) * H + h) * Wd;

    // ---- stage W1, W2(T) into LDS: coalesced float4 copies ----
    {
        const float4* __restrict__ g1 = reinterpret_cast<const float4*>(W1h);
        const float4* __restrict__ g2 = reinterpret_cast<const float4*>(W2h);
        float4* s1 = reinterpret_cast<float4*>(sW1);
        float4* s2 = reinterpret_cast<float4*>(sW2);
#pragma unroll
        for (int r = 0; r < 4; ++r) s1[tid + 256 * r] = g1[tid + 256 * r];
#pragma unroll
        for (int r = 0; r < 4; ++r) s2[tid + 256 * r] = g2[tid + 256 * r];
    }

    // ---- a2 accumulators: 16 own-quarter outputs x 4 pixels, seeded b2 ----
    float a200[16], a201[16], a210[16], a211[16];
#pragma unroll
    for (int j = 0; j < 16; ++j) {
        const float bb = b2h[cb + j];
        a200[j] = bb; a201[j] = bb; a210[j] = bb; a211[j] = bb;
    }

    __syncthreads();   // staging complete

    // ======== layers 1+2 (x scoped here; freed before layer 3) ========
    {
        // x: own 16 channels x 4 pixels (HBM once)
        float x00[16], x01[16], x10[16], x11[16];
#pragma unroll
        for (int ch = 0; ch < 16; ++ch) {
            const size_t o = (size_t)ch * HW;
            x00[ch] = xb0[o + wc0];
            x01[ch] = xb0[o + wc1];
            x10[ch] = xb1[o + wc0];
            x11[ch] = xb1[o + wc1];
        }

#pragma unroll 1
        for (int c = 0; c < C; ++c) {
            float p00 = 0.0f, p01 = 0.0f, p10 = 0.0f, p11 = 0.0f;
#pragma unroll
            for (int i = 0; i < 4; ++i) {
                const float4 wv = *reinterpret_cast<const float4*>(&sW1[c * C + cb + 4 * i]);
                p00 = fmaf(wv.x, x00[4*i+0], p00);
                p00 = fmaf(wv.y, x00[4*i+1], p00);
                p00 = fmaf(wv.z, x00[4*i+2], p00);
                p00 = fmaf(wv.w, x00[4*i+3], p00);
                p01 = fmaf(wv.x, x01[4*i+0], p01);
                p01 = fmaf(wv.y, x01[4*i+1], p01);
                p01 = fmaf(wv.z, x01[4*i+2], p01);
                p01 = fmaf(wv.w, x01[4*i+3], p01);
                p10 = fmaf(wv.x, x10[4*i+0], p10);
                p10 = fmaf(wv.y, x10[4*i+1], p10);
                p10 = fmaf(wv.z, x10[4*i+2], p10);
                p10 = fmaf(wv.w, x10[4*i+3], p10);
                p11 = fmaf(wv.x, x11[4*i+0], p11);
                p11 = fmaf(wv.y, x11[4*i+1], p11);
                p11 = fmaf(wv.z, x11[4*i+2], p11);
                p11 = fmaf(wv.w, x11[4*i+3], p11);
            }
            // combine the 4 channel-quarters (lanes l, l^16, l^32, l^48)
            p00 += __shfl_xor(p00, 16); p00 += __shfl_xor(p00, 32);
            p01 += __shfl_xor(p01, 16); p01 += __shfl_xor(p01, 32);
            p10 += __shfl_xor(p10, 16); p10 += __shfl_xor(p10, 32);
            p11 += __shfl_xor(p11, 16); p11 += __shfl_xor(p11, 32);

            const float b1c = b1h[c];     // uniform s_load
            const float a0 = lrelu(b1c + p00);
            const float a1 = lrelu(b1c + p01);
            const float a2v = lrelu(b1c + p10);
            const float a3 = lrelu(b1c + p11);

            if constexpr (USE_WT) {
#pragma unroll
                for (int i = 0; i < 4; ++i) {
                    const float4 wv = *reinterpret_cast<const float4*>(&sW2[c * C + cb + 4 * i]);
                    a200[4*i+0] = fmaf(wv.x, a0, a200[4*i+0]);
                    a200[4*i+1] = fmaf(wv.y, a0, a200[4*i+1]);
                    a200[4*i+2] = fmaf(wv.z, a0, a200[4*i+2]);
                    a200[4*i+3] = fmaf(wv.w, a0, a200[4*i+3]);
                    a201[4*i+0] = fmaf(wv.x, a1, a201[4*i+0]);
                    a201[4*i+1] = fmaf(wv.y, a1, a201[4*i+1]);
                    a201[4*i+2] = fmaf(wv.z, a1, a201[4*i+2]);
                    a201[4*i+3] = fmaf(wv.w, a1, a201[4*i+3]);
                    a210[4*i+0] = fmaf(wv.x, a2v, a210[4*i+0]);
                    a210[4*i+1] = fmaf(wv.y, a2v, a210[4*i+1]);
                    a210[4*i+2] = fmaf(wv.z, a2v, a210[4*i+2]);
                    a210[4*i+3] = fmaf(wv.w, a2v, a210[4*i+3]);
                    a211[4*i+0] = fmaf(wv.x, a3, a211[4*i+0]);
                    a211[4*i+1] = fmaf(wv.y, a3, a211[4*i+1]);
                    a211[4*i+2] = fmaf(wv.z, a3, a211[4*i+2]);
                    a211[4*i+3] = fmaf(wv.w, a3, a211[4*i+3]);
                }
            } else {
                // fallback: strided column reads on untransposed W2
#pragma unroll
                for (int j = 0; j < 16; ++j) {
                    const float wv = sW2[(cb + j) * C + c];
                    a200[j] = fmaf(wv, a0,  a200[j]);
                    a201[j] = fmaf(wv, a1,  a201[j]);
                    a210[j] = fmaf(wv, a2v, a210[j]);
                    a211[j] = fmaf(wv, a3,  a211[j]);
                }
            }
        }
    } // x arrays die here

#pragma unroll
    for (int j = 0; j < 16; ++j) {
        a200[j] = lrelu(a200[j]); a201[j] = lrelu(a201[j]);
        a210[j] = lrelu(a210[j]); a211[j] = lrelu(a211[j]);
    }

    // ---- layer 3 + argmax; W3 from global (L2-hot), k-tiles of 4 ----
    float be00 = -3.402823466e38f, be01 = be00, be10 = be00, be11 = be00;
    int   bi00 = 0, bi01 = 0, bi10 = 0, bi11 = 0;
#pragma unroll 1
    for (int kt = 0; kt < K / 4; ++kt) {
        float s00[4] = {0,0,0,0}, s01[4] = {0,0,0,0};
        float s10[4] = {0,0,0,0}, s11[4] = {0,0,0,0};
#pragma unroll
        for (int j = 0; j < 4; ++j) {
            const float4* __restrict__ w3r =
                reinterpret_cast<const float4*>(&W3h[(kt*4 + j) * C + cb]);
#pragma unroll
            for (int i = 0; i < 4; ++i) {
                const float4 wv = w3r[i];
                s00[j] = fmaf(wv.x, a200[4*i+0], s00[j]);
                s00[j] = fmaf(wv.y, a200[4*i+1], s00[j]);
                s00[j] = fmaf(wv.z, a200[4*i+2], s00[j]);
                s00[j] = fmaf(wv.w, a200[4*i+3], s00[j]);
                s01[j] = fmaf(wv.x, a201[4*i+0], s01[j]);
                s01[j] = fmaf(wv.y, a201[4*i+1], s01[j]);
                s01[j] = fmaf(wv.z, a201[4*i+2], s01[j]);
                s01[j] = fmaf(wv.w, a201[4*i+3], s01[j]);
                s10[j] = fmaf(wv.x, a210[4*i+0], s10[j]);
                s10[j] = fmaf(wv.y, a210[4*i+1], s10[j]);
                s10[j] = fmaf(wv.z, a210[4*i+2], s10[j]);
                s10[j] = fmaf(wv.w, a210[4*i+3], s10[j]);
                s11[j] = fmaf(wv.x, a211[4*i+0], s11[j]);
                s11[j] = fmaf(wv.y, a211[4*i+1], s11[j]);
                s11[j] = fmaf(wv.z, a211[4*i+2], s11[j]);
                s11[j] = fmaf(wv.w, a211[4*i+3], s11[j]);
            }
        }
#pragma unroll
        for (int j = 0; j < 4; ++j) {
            const float bj = b3h[kt*4 + j];                         // uniform
            float t00 = s00[j]; t00 += __shfl_xor(t00, 16); t00 += __shfl_xor(t00, 32); t00 += bj;
            float t01 = s01[j]; t01 += __shfl_xor(t01, 16); t01 += __shfl_xor(t01, 32); t01 += bj;
            float t10 = s10[j]; t10 += __shfl_xor(t10, 16); t10 += __shfl_xor(t10, 32); t10 += bj;
            float t11 = s11[j]; t11 += __shfl_xor(t11, 16); t11 += __shfl_xor(t11, 32); t11 += bj;
            const int k = kt*4 + j;
            if (t00 > be00) { be00 = t00; bi00 = k; }   // strict > = first max
            if (t01 > be01) { be01 = t01; bi01 = k; }
            if (t10 > be10) { be10 = t10; bi10 = k; }
            if (t11 > be11) { be11 = t11; bi11 = k; }
        }
    }

    // ---- conditional regression; x reloaded (L2/L3-hot), Wr gathered ----
    const int fl00 = h * K + bi00, fl01 = h * K + bi01;
    const int fl10 = h * K + bi10, fl11 = h * K + bi11;

    float r0_00, r1_00, r0_01, r1_01, r0_10, r1_10, r0_11, r1_11;
#pragma unroll
    for (int p = 0; p < 4; ++p) {
        const int   flat = (p == 0) ? fl00 : (p == 1) ? fl01 : (p == 2) ? fl10 : fl11;
        const int   wcp  = (p & 1) ? wc1 : wc0;
        const float* __restrict__ xb = (p < 2) ? xb0 : xb1;
        const float* __restrict__ wrp = Wr + (size_t)flat * C * 2 + (size_t)cb * 2;
        float f0 = 0.0f, f1 = 0.0f;
#pragma unroll
        for (int t = 0; t < 8; ++t) {    // 16 channels, 2 per float4 of Wr
            const float4 q = *reinterpret_cast<const float4*>(&wrp[4 * t]);
            const float xa = xb[(size_t)(2*t+0) * HW + wcp];
            const float xbv = xb[(size_t)(2*t+1) * HW + wcp];
            f0 = fmaf(xa,  q.x, f0);
            f1 = fmaf(xa,  q.y, f1);
            f0 = fmaf(xbv, q.z, f0);
            f1 = fmaf(xbv, q.w, f1);
        }
        f0 += __shfl_xor(f0, 16); f0 += __shfl_xor(f0, 32);
        f1 += __shfl_xor(f1, 16); f1 += __shfl_xor(f1, 32);
        const float r0 = lrelu(f0 + br[2 * flat + 0]);
        const float r1 = lrelu(f1 + br[2 * flat + 1]);
        if (p == 0)      { r0_00 = r0; r1_00 = r1; }
        else if (p == 1) { r0_01 = r0; r1_01 = r1; }
        else if (p == 2) { r0_10 = r0; r1_10 = r1; }
        else             { r0_11 = r0; r1_11 = r1; }
    }

    if (qtr == 0) {
        const size_t HWall = (size_t)B * H * Wd;
        const size_t rowb0 = ((size_t)0 * H + h) * Wd;
        const size_t rowb1 = ((size_t)1 * H + h) * Wd;
        if (v0) {
            out[rowb0 + w0]         = ((float)fl00 + r0_00) * (1.0f / K);
            out[HWall + rowb0 + w0] = lrelu(r1_00);     // double lrelu, per ref
            out[rowb1 + w0]         = ((float)fl10 + r0_10) * (1.0f / K);
            out[HWall + rowb1 + w0] = lrelu(r1_10);
        }
        if (v1) {
            out[rowb0 + w1]         = ((float)fl01 + r0_01) * (1.0f / K);
            out[HWall + rowb0 + w1] = lrelu(r1_01);
            out[rowb1 + w1]         = ((float)fl11 + r0_11) * (1.0f / K);
            out[HWall + rowb1 + w1] = lrelu(r1_11);
        }
    }
}

} // namespace

extern "C" void kernel_launch(void* const* d_in, const int* in_sizes, int n_in,
                              void* d_out, int out_size, void* d_ws, size_t ws_size,
                              hipStream_t stream) {
    const float* x  = (const float*)d_in[0];
    const float* W1 = (const float*)d_in[1];
    const float* b1 = (const float*)d_in[2];
    const float* W2 = (const float*)d_in[3];
    const float* b2 = (const float*)d_in[4];
    const float* W3 = (const float*)d_in[5];
    const float* b3 = (const float*)d_in[6];
    const float* Wr = (const float*)d_in[7];
    const float* br = (const float*)d_in[8];
    float* out = (float*)d_out;

    dim3 grid(NBLK);
    dim3 block(256);

    if (ws_size >= W2T_BYTES) {
        float* W2T = (float*)d_ws;
        hipLaunchKernelGGL(transpose_w2, dim3(H), dim3(256), 0, stream, W2, W2T);
        hipLaunchKernelGGL((reg1stage_kernel<true>), grid, block, 0, stream,
                           x, W1, b1, W2T, b2, W3, b3, Wr, br, out);
    } else {
        hipLaunchKernelGGL((reg1stage_kernel<false>), grid, block, 0, stream,
                           x, W1, b1, W2, b2, W3, b3, Wr, br, out);
    }
}